// Round 4
// baseline (4305.755 us; speedup 1.0000x reference)
//
#include <hip/hip_runtime.h>
#include <math.h>

#define HIDDEN  2048
#define NEXP    256
#define TOPK    8
#define NGROUP  8
#define TKG     4
#define GSZ     32
#define TM      32                 // tokens per block
#define KC      32                 // k-chunk (two 16-elem SSE groups)
#define NCHUNK  (HIDDEN / KC)      // 64
#define LGSTR   (NEXP + 2)         // logits row stride in pool
#define WSZ     (NEXP * KC)        // 8192 floats per W buffer
#define XSZ     (TM * KC)          // 1024 floats per X buffer

// Bit-exact emulation of numpy c_einsum's f32 dot kernel (SSE baseline):
//   - 4 lane-chains (k mod 4), mul/add separately rounded (no FMA)
//   - 16-elem groups ascending; within a group float4s accumulated reversed
//   - final combine (A0+A1)+(A2+A3)
// GEMM numerics/order identical to the r3 passing kernel; only the staging
// schedule changed (double-buffered LDS, loads 2 chunks ahead, 1 barrier/chunk).
__global__ __launch_bounds__(256, 2) void moe_gate_main(
    const float* __restrict__ X,      // [T, HIDDEN]
    const float* __restrict__ W,      // [NEXP, HIDDEN]
    float* __restrict__ out,          // [T*8 idx][T*8 w][1 loss]
    double* __restrict__ S_ws,        // [NEXP]
    int* __restrict__ cnt_ws,         // [NEXP]
    int T)
{
#pragma clang fp contract(off)
    __shared__ __align__(16) float smem[2 * WSZ + 2 * XSZ];   // 72 KB: W dbuf + X dbuf; logits overlay
    __shared__ float dmax[TM];
    __shared__ float den[TM];

    const int tid = threadIdx.x;
    const int tg  = tid >> 6;        // wave id -> token octet (wave-uniform)
    const int exq = tid & 63;        // expert base lane
    const int t0  = blockIdx.x * TM;
    const int swz = exq & 7;

    // staging geometry
    const int xrow  = tid >> 3;                  // X token row
    const int col4  = tid & 7;                   // 16B column
    const int wswz  = (tid >> 3) & 7;            // W store swizzle (same for all 8 its)
    const int wcol  = (col4 ^ wswz) * 4;
    const float* Xp = X + (size_t)(t0 + xrow) * HIDDEN + 4 * col4;
    const float* Wp = W + (size_t)(tid >> 3) * HIDDEN + 4 * col4;

    float acc_x[8][4], acc_y[8][4], acc_z[8][4], acc_w[8][4];
#pragma unroll
    for (int i = 0; i < 8; ++i)
#pragma unroll
        for (int j = 0; j < 4; ++j) { acc_x[i][j] = 0.f; acc_y[i][j] = 0.f; acc_z[i][j] = 0.f; acc_w[i][j] = 0.f; }

    float4 wreg[8]; float4 xreg;

#define LOADC(c)                                                             \
    do {                                                                     \
        const int k0_ = (c) * KC;                                            \
        xreg = *(const float4*)(Xp + k0_);                                   \
        _Pragma("unroll")                                                    \
        for (int it = 0; it < 8; ++it)                                       \
            wreg[it] = *(const float4*)(Wp + (size_t)it * 32 * HIDDEN + k0_);\
    } while (0)

#define STOREC(buf)                                                          \
    do {                                                                     \
        float* wd_ = smem + (buf) * WSZ;                                     \
        float* xd_ = smem + 2 * WSZ + (buf) * XSZ;                           \
        *(float4*)(xd_ + tid * 4) = xreg;                                    \
        _Pragma("unroll")                                                    \
        for (int it = 0; it < 8; ++it)                                       \
            *(float4*)(wd_ + (it * 32 + (tid >> 3)) * KC + wcol) = wreg[it]; \
    } while (0)

    // prologue: buf0 <- chunk0; regs <- chunk1 (in flight)
    LOADC(0);
    STOREC(0);
    LOADC(1);
    __syncthreads();

#pragma unroll 2
    for (int c = 0; c < NCHUNK; ++c) {
        const int cur = c & 1;
        if (c + 1 < NCHUNK) {
            STOREC((c + 1) & 1);           // write next chunk into the idle buffer
            if (c + 2 < NCHUNK) LOADC(c + 2);
        }
        const float* ws_ = smem + cur * WSZ;
        const float* xs_ = smem + 2 * WSZ + cur * XSZ;
        // two 16-elem groups, vectors reversed within each (SSE chain order)
#pragma unroll
        for (int blk = 0; blk < 2; ++blk) {
#pragma unroll
            for (int vv = 3; vv >= 0; --vv) {
                const int k4 = blk * 4 + vv;
                const int sc = (k4 ^ swz) * 4;
                float4 wv[4];
#pragma unroll
                for (int j = 0; j < 4; ++j)
                    wv[j] = *(const float4*)(ws_ + (exq + 64 * j) * KC + sc);
#pragma unroll
                for (int i = 0; i < 8; ++i) {
                    const float4 xv = *(const float4*)(xs_ + (tg * 8 + i) * KC + 4 * k4); // broadcast
#pragma unroll
                    for (int j = 0; j < 4; ++j) {
                        acc_x[i][j] = __fadd_rn(acc_x[i][j], __fmul_rn(xv.x, wv[j].x));
                        acc_y[i][j] = __fadd_rn(acc_y[i][j], __fmul_rn(xv.y, wv[j].y));
                        acc_z[i][j] = __fadd_rn(acc_z[i][j], __fmul_rn(xv.z, wv[j].z));
                        acc_w[i][j] = __fadd_rn(acc_w[i][j], __fmul_rn(xv.w, wv[j].w));
                    }
                }
            }
        }
        __syncthreads();
    }

    // logits into pool (overlays W/X buffers; all staging reads done - barrier above)
    float* pool = smem;
#pragma unroll
    for (int i = 0; i < 8; ++i)
#pragma unroll
        for (int j = 0; j < 4; ++j)
            pool[(tg * 8 + i) * LGSTR + exq + 64 * j] =
                __fadd_rn(__fadd_rn(acc_x[i][j], acc_y[i][j]),
                          __fadd_rn(acc_z[i][j], acc_w[i][j]));
    __syncthreads();

    // ---- per-token selection: grouped top-4, global top-8, softmax weights ----
    if (tid < TM) {
        const int t = tid;
        float cv[NGROUP * TKG];
        int   ci[NGROUP * TKG];
        float gmax = -3.0e38f;

        for (int g = 0; g < NGROUP; ++g) {
            float v4[TKG] = { -3.0e38f, -3.0e38f, -3.0e38f, -3.0e38f };
            int   i4[TKG] = { 0, 0, 0, 0 };
            for (int jj = 0; jj < GSZ; ++jj) {
                const float v = pool[t * LGSTR + g * GSZ + jj];
                if (v > gmax) gmax = v;
                if (v > v4[TKG - 1]) {          // strict > : stable (lower idx first)
                    int q = TKG - 1;
                    while (q > 0 && v > v4[q - 1]) {
                        v4[q] = v4[q - 1]; i4[q] = i4[q - 1]; --q;
                    }
                    v4[q] = v; i4[q] = jj;
                }
            }
#pragma unroll
            for (int r = 0; r < TKG; ++r) { cv[g * TKG + r] = v4[r]; ci[g * TKG + r] = i4[r]; }
        }

        float v8[TOPK]; int p8[TOPK];
#pragma unroll
        for (int k = 0; k < TOPK; ++k) { v8[k] = -3.0e38f; p8[k] = 0; }
        for (int p = 0; p < NGROUP * TKG; ++p) {
            const float v = cv[p];
            if (v > v8[TOPK - 1]) {             // strict > : stable by candidate pos
                int q = TOPK - 1;
                while (q > 0 && v > v8[q - 1]) {
                    v8[q] = v8[q - 1]; p8[q] = p8[q - 1]; --q;
                }
                v8[q] = v; p8[q] = p;
            }
        }

        float w8[TOPK]; float ssum = 0.f;
#pragma unroll
        for (int k = 0; k < TOPK; ++k) {
            w8[k] = expf(v8[k] - v8[0]);
            ssum += w8[k];
        }

        const size_t row = (size_t)(t0 + t) * TOPK;
#pragma unroll
        for (int k = 0; k < TOPK; ++k) {
            const int pos = p8[k];
            const int ex  = (pos >> 2) * GSZ + ci[pos];
            out[row + k] = (float)ex;
            out[(size_t)T * TOPK + row + k] = w8[k] / ssum;
            atomicAdd(&cnt_ws[ex], 1);
        }

        float dsum = 0.f;
        for (int e2 = 0; e2 < NEXP; ++e2)
            dsum += expf(pool[t * LGSTR + e2] - gmax);
        dmax[t] = gmax;
        den[t]  = dsum;
    }
    __syncthreads();

    // ---- per-expert partial sum of probs over this block's tokens ----
    double part = 0.0;
#pragma unroll
    for (int t = 0; t < TM; ++t)
        part += (double)(expf(pool[t * LGSTR + tid] - dmax[t]) / den[t]);
    atomicAdd(&S_ws[tid], part);
#undef LOADC
#undef STOREC
}

// ---------------- tiny loss-finalize kernel ----------------
__global__ __launch_bounds__(256) void moe_gate_loss(
    const double* __restrict__ S_ws, const int* __restrict__ cnt_ws,
    float* __restrict__ out, int T)
{
    __shared__ double red[NEXP];
    const int e = threadIdx.x;
    const double S = S_ws[e];
    const double c = (double)cnt_ws[e];
    const double Td = (double)T;
    const double aux = (c / Td) * (S / Td);
    double z = log(S); z *= z;

    red[e] = aux; __syncthreads();
    for (int s = 128; s > 0; s >>= 1) { if (e < s) red[e] += red[e + s]; __syncthreads(); }
    const double auxsum = red[0];
    __syncthreads();
    red[e] = z; __syncthreads();
    for (int s = 128; s > 0; s >>= 1) { if (e < s) red[e] += red[e + s]; __syncthreads(); }
    if (e == 0)
        out[(size_t)T * TOPK * 2] = (float)(auxsum * 1.0e-3 + (red[0] / (double)NEXP) * 1.0e-4);
}

extern "C" void kernel_launch(void* const* d_in, const int* in_sizes, int n_in,
                              void* d_out, int out_size, void* d_ws, size_t ws_size,
                              hipStream_t stream)
{
    const float* X = (const float*)d_in[0];
    const float* W = (const float*)d_in[1];
    float* out = (float*)d_out;
    const int T = in_sizes[0] / HIDDEN;   // 16384

    double* S_ws   = (double*)d_ws;
    int*    cnt_ws = (int*)((char*)d_ws + NEXP * sizeof(double));

    hipMemsetAsync(d_ws, 0, NEXP * (sizeof(double) + sizeof(int)), stream);

    moe_gate_main<<<dim3(T / TM), dim3(256), 0, stream>>>(X, W, out, S_ws, cnt_ws, T);
    moe_gate_loss<<<dim3(1), dim3(256), 0, stream>>>(S_ws, cnt_ws, out, T);
}

// Round 5
// 523.771 us; speedup vs baseline: 8.2207x; 8.2207x over previous
//
#include <hip/hip_runtime.h>
#include <math.h>

#define HIDDEN  2048
#define NEXP    256
#define TOPK    8
#define NGROUP  8
#define TKG     4
#define GSZ     32
#define TM      32                 // tokens per block
#define KC      32                 // k-chunk (two 16-elem SSE groups)
#define NCHUNK  (HIDDEN / KC)      // 64
#define LGSTR   (NEXP + 2)         // logits row stride in pool

// Bit-exact emulation of numpy c_einsum's f32 dot kernel (SSE baseline):
//   - 4 lane-chains (k mod 4), mul/add separately rounded (no FMA)
//   - 16-elem groups ascending; within a group float4s accumulated reversed
//   - final combine (A0+A1)+(A2+A3)
// Numerics/order identical to the r3 passing kernel. Only the work split
// changed: 512 threads (8 waves), wave = 4 tokens, lane = 4 experts ->
// acc halves to 64 regs, grid 512 blocks = 2 blocks/CU = 4 waves/SIMD.
__global__ __launch_bounds__(512, 4) void moe_gate_main(
    const float* __restrict__ X,      // [T, HIDDEN]
    const float* __restrict__ W,      // [NEXP, HIDDEN]
    float* __restrict__ out,          // [T*8 idx][T*8 w][1 loss]
    double* __restrict__ S_ws,        // [NEXP]
    int* __restrict__ cnt_ws,         // [NEXP]
    int T)
{
#pragma clang fp contract(off)
    __shared__ __align__(16) float xs[TM][KC];          // 4 KB
    __shared__ __align__(16) float pool[TM * LGSTR];    // 33 KB: W tile during GEMM, logits after
    __shared__ float dmax[TM];
    __shared__ float den[TM];

    const int tid = threadIdx.x;
    const int tq  = (tid >> 6) * 4;  // wave -> token quartet base (wave-uniform)
    const int exq = tid & 63;        // expert base lane
    const int t0  = blockIdx.x * TM;
    const int swz = exq & 7;

    float4 acc[4][4];                // [token][expert-quad], 64 floats
#pragma unroll
    for (int i = 0; i < 4; ++i)
#pragma unroll
        for (int j = 0; j < 4; ++j) acc[i][j] = make_float4(0.f, 0.f, 0.f, 0.f);

    for (int c = 0; c < NCHUNK; ++c) {
        const int k0 = c * KC;
        __syncthreads();
        // stage X chunk [32 tokens][32 k]: threads 0..255, one float4 each
        if (tid < 256) {
            const int trow = tid >> 3, col4 = tid & 7;
            const float4 v = *(const float4*)(X + (size_t)(t0 + trow) * HIDDEN + k0 + 4 * col4);
            *(float4*)&xs[trow][4 * col4] = v;
        }
        // stage W chunk [256 experts][32 k], XOR-swizzled 16B columns
#pragma unroll
        for (int it = 0; it < 4; ++it) {
            const int f4  = it * 512 + tid;
            const int row = f4 >> 3, col4 = f4 & 7;
            const float4 v = *(const float4*)(W + (size_t)row * HIDDEN + k0 + 4 * col4);
            *(float4*)&pool[row * KC + ((col4 ^ (row & 7)) * 4)] = v;
        }
        __syncthreads();
        // two 16-elem groups, vectors reversed within each (SSE chain order)
#pragma unroll
        for (int blk = 0; blk < 2; ++blk) {
#pragma unroll
            for (int vv = 3; vv >= 0; --vv) {
                const int k4 = blk * 4 + vv;
                const int sc = (k4 ^ swz) * 4;
                float4 wv[4];
#pragma unroll
                for (int j = 0; j < 4; ++j)
                    wv[j] = *(const float4*)&pool[(exq + 64 * j) * KC + sc];
#pragma unroll
                for (int i = 0; i < 4; ++i) {
                    const float4 xv = *(const float4*)&xs[tq + i][4 * k4];   // broadcast
#pragma unroll
                    for (int j = 0; j < 4; ++j) {
                        // ascending k within each mod-4 chain -- DO NOT reorder
                        acc[i][j].x = __fadd_rn(acc[i][j].x, __fmul_rn(xv.x, wv[j].x));
                        acc[i][j].y = __fadd_rn(acc[i][j].y, __fmul_rn(xv.y, wv[j].y));
                        acc[i][j].z = __fadd_rn(acc[i][j].z, __fmul_rn(xv.z, wv[j].z));
                        acc[i][j].w = __fadd_rn(acc[i][j].w, __fmul_rn(xv.w, wv[j].w));
                    }
                }
            }
        }
    }

    __syncthreads();   // all W-tile reads done; pool becomes the logits buffer
#pragma unroll
    for (int i = 0; i < 4; ++i)
#pragma unroll
        for (int j = 0; j < 4; ++j) {
            const float4 a = acc[i][j];
            // SSE3 hadd x2: (A0+A1)+(A2+A3)
            pool[(tq + i) * LGSTR + exq + 64 * j] =
                __fadd_rn(__fadd_rn(a.x, a.y), __fadd_rn(a.z, a.w));
        }
    __syncthreads();

    // ---- per-token selection: grouped top-4, global top-8, softmax weights ----
    if (tid < TM) {
        const int t = tid;
        float cv[NGROUP * TKG];
        int   ci[NGROUP * TKG];
        float gmax = -3.0e38f;

        for (int g = 0; g < NGROUP; ++g) {
            float v4[TKG] = { -3.0e38f, -3.0e38f, -3.0e38f, -3.0e38f };
            int   i4[TKG] = { 0, 0, 0, 0 };
            for (int jj = 0; jj < GSZ; ++jj) {
                const float v = pool[t * LGSTR + g * GSZ + jj];
                if (v > gmax) gmax = v;
                if (v > v4[TKG - 1]) {          // strict > : stable (lower idx first)
                    int q = TKG - 1;
                    while (q > 0 && v > v4[q - 1]) {
                        v4[q] = v4[q - 1]; i4[q] = i4[q - 1]; --q;
                    }
                    v4[q] = v; i4[q] = jj;
                }
            }
#pragma unroll
            for (int r = 0; r < TKG; ++r) { cv[g * TKG + r] = v4[r]; ci[g * TKG + r] = i4[r]; }
        }

        float v8[TOPK]; int p8[TOPK];
#pragma unroll
        for (int k = 0; k < TOPK; ++k) { v8[k] = -3.0e38f; p8[k] = 0; }
        for (int p = 0; p < NGROUP * TKG; ++p) {
            const float v = cv[p];
            if (v > v8[TOPK - 1]) {             // strict > : stable by candidate pos
                int q = TOPK - 1;
                while (q > 0 && v > v8[q - 1]) {
                    v8[q] = v8[q - 1]; p8[q] = p8[q - 1]; --q;
                }
                v8[q] = v; p8[q] = p;
            }
        }

        float w8[TOPK]; float ssum = 0.f;
#pragma unroll
        for (int k = 0; k < TOPK; ++k) {
            w8[k] = expf(v8[k] - v8[0]);
            ssum += w8[k];
        }

        const size_t row = (size_t)(t0 + t) * TOPK;
#pragma unroll
        for (int k = 0; k < TOPK; ++k) {
            const int pos = p8[k];
            const int ex  = (pos >> 2) * GSZ + ci[pos];
            out[row + k] = (float)ex;
            out[(size_t)T * TOPK + row + k] = w8[k] / ssum;
            atomicAdd(&cnt_ws[ex], 1);
        }

        float dsum = 0.f;
        for (int e2 = 0; e2 < NEXP; ++e2)
            dsum += expf(pool[t * LGSTR + e2] - gmax);
        dmax[t] = gmax;
        den[t]  = dsum;
    }
    __syncthreads();

    // ---- per-expert partial sum of probs over this block's tokens ----
    if (tid < NEXP) {
        double part = 0.0;
#pragma unroll
        for (int t = 0; t < TM; ++t)
            part += (double)(expf(pool[t * LGSTR + tid] - dmax[t]) / den[t]);
        atomicAdd(&S_ws[tid], part);
    }
}

// ---------------- tiny loss-finalize kernel ----------------
__global__ __launch_bounds__(256) void moe_gate_loss(
    const double* __restrict__ S_ws, const int* __restrict__ cnt_ws,
    float* __restrict__ out, int T)
{
    __shared__ double red[NEXP];
    const int e = threadIdx.x;
    const double S = S_ws[e];
    const double c = (double)cnt_ws[e];
    const double Td = (double)T;
    const double aux = (c / Td) * (S / Td);
    double z = log(S); z *= z;

    red[e] = aux; __syncthreads();
    for (int s = 128; s > 0; s >>= 1) { if (e < s) red[e] += red[e + s]; __syncthreads(); }
    const double auxsum = red[0];
    __syncthreads();
    red[e] = z; __syncthreads();
    for (int s = 128; s > 0; s >>= 1) { if (e < s) red[e] += red[e + s]; __syncthreads(); }
    if (e == 0)
        out[(size_t)T * TOPK * 2] = (float)(auxsum * 1.0e-3 + (red[0] / (double)NEXP) * 1.0e-4);
}

extern "C" void kernel_launch(void* const* d_in, const int* in_sizes, int n_in,
                              void* d_out, int out_size, void* d_ws, size_t ws_size,
                              hipStream_t stream)
{
    const float* X = (const float*)d_in[0];
    const float* W = (const float*)d_in[1];
    float* out = (float*)d_out;
    const int T = in_sizes[0] / HIDDEN;   // 16384

    double* S_ws   = (double*)d_ws;
    int*    cnt_ws = (int*)((char*)d_ws + NEXP * sizeof(double));

    hipMemsetAsync(d_ws, 0, NEXP * (sizeof(double) + sizeof(int)), stream);

    moe_gate_main<<<dim3(T / TM), dim3(512), 0, stream>>>(X, W, out, S_ws, cnt_ws, T);
    moe_gate_loss<<<dim3(1), dim3(256), 0, stream>>>(S_ws, cnt_ws, out, T);
}